// Round 10
// baseline (172.958 us; speedup 1.0000x reference)
//
#include <hip/hip_runtime.h>
#include <hip/hip_bf16.h>

// RelationAwareSelfAttention  N=500, DM=DK=DV=2048, KWIN=10
// Round 16: revert Y atomics (R15 regression). BN=32 / D=2 core (24KB LDS,
// launch_bounds(256,5) -> 5 blocks/CU): qkvt 1536 blk, S 1024, AV 512, Y 512.
// TLP (blocks/CU) is the proven lever (R12-R14: ~linear time conversion).
// Sync skeleton (2-barrier, counted vmcnt, T21 granule swizzle) unchanged.
// 6 launches.

#define N_TOK 500
#define MP 512
#define DM 2048
#define KWIN_ 10
#define NREL 21

typedef __hip_bfloat16 bf16;
typedef __attribute__((ext_vector_type(8))) short short8;
typedef __attribute__((ext_vector_type(4))) float floatx4;

#define NS 262144L  // 512*512

__device__ inline float bfj(const short8& v, int j) {
  return __bfloat162float(((const bf16*)&v)[j]);
}

__device__ __forceinline__ void gload16(const bf16* g, bf16* l) {
  __builtin_amdgcn_global_load_lds(
      (const __attribute__((address_space(1))) void*)g,
      (__attribute__((address_space(3))) void*)l, 16, 0, 0);
}

// ---------------- prep: weights transpose+cvt, X/wk cvt (verified) --------
__global__ __launch_bounds__(256) void prep(
    const float* __restrict__ Wq, const float* __restrict__ Wk,
    const float* __restrict__ Wv, const float* __restrict__ Wo,
    const float* __restrict__ X, const float* __restrict__ wk,
    bf16* __restrict__ WqkT, bf16* __restrict__ WvT, bf16* __restrict__ WoT,
    bf16* __restrict__ Xb, bf16* __restrict__ wkb) {
  int z = blockIdx.z;
  int tid = threadIdx.x;
  if (z == 4) {  // row conversions
    int row = blockIdx.y * 32 + blockIdx.x;
    int c0 = tid * 8;
    bf16 v[8];
    if (row < MP) {
      if (row < N_TOK) {
        const float* p = X + (long)row * DM + c0;
#pragma unroll
        for (int j = 0; j < 8; ++j) v[j] = __float2bfloat16(p[j]);
      } else {
#pragma unroll
        for (int j = 0; j < 8; ++j) v[j] = __float2bfloat16(0.f);
      }
      *(short8*)(Xb + (long)row * DM + c0) = *(short8*)v;
    } else if (row < MP + NREL) {
      int r = row - MP;
      const float* p = wk + (long)r * DM + c0;
#pragma unroll
      for (int j = 0; j < 8; ++j) v[j] = __float2bfloat16(p[j]);
      *(short8*)(wkb + (long)r * DM + c0) = *(short8*)v;
    }
    return;
  }
  const float* W = (z == 0) ? Wq : (z == 1) ? Wk : (z == 2) ? Wv : Wo;
  bf16* Out = (z == 0) ? WqkT
            : (z == 1) ? (WqkT + (long)DM * DM)
            : (z == 2) ? WvT : WoT;
  __shared__ float t[64][68];  // XOR-swizzled granules, conflict-free both sides
  int k0 = blockIdx.y * 64, n0 = blockIdx.x * 64;
  int rr = tid >> 4, cc = (tid & 15) * 4;
  int gsw = cc >> 2;
#pragma unroll
  for (int p = 0; p < 4; ++p) {
    int r = rr + 16 * p;
    float4 v = *(const float4*)(W + (long)(k0 + r) * DM + n0 + cc);
    *(float4*)&t[r][(gsw ^ (r & 3)) * 4] = v;
  }
  __syncthreads();
#pragma unroll
  for (int s0 = 0; s0 < 2; ++s0) {
    int s = tid + s0 * 256;
    int n = s >> 3, c = s & 7;  // 8 lanes per out row -> 128B contiguous
    bf16 v[8];
#pragma unroll
    for (int j = 0; j < 8; ++j) {
      int rowt = c * 8 + j;
      int col = ((n >> 2) ^ (rowt & 3)) * 4 + (n & 3);
      v[j] = __float2bfloat16(t[rowt][col]);
    }
    *(short8*)(Out + (long)(n0 + n) * DM + k0 + c * 8) = *(short8*)v;
  }
}

// ---------------- gemm core: 64xBN tile, BK=64, D=2 gload_lds dbuf --------
// C[M,N] = A[M,K] @ B[N,K]^T over K-slice [kStart, kStart+kLen).
// 4 waves 2x2; wave tile 32 x BN/2. BN=32: acc 2x1, LDS 24 KB -> 5+ blocks/CU.
// Staging: gload_lds issue = 64 lanes x 16B = 8 rows x 128B, linear dest.
// Swizzle: phys granule p of row r holds data granule p ^ (r&7); inverse
// permutation applied to the per-lane GLOBAL source granule (T21), same XOR
// on the LDS read -> <=2-way bank conflicts on ds_read_b128.
// Double buffer, lookahead 1: tile t+1 staged at iter t, vmcnt leaves LPT.
// Cross-block TLP (5/CU) hides what the shallow pipeline doesn't.
// OUT: 0 -> f32 store, 1 -> bf16 store. Store guard: row < mLim.
template <int BN, int OUT>
__device__ __forceinline__ void gemm_core(
    bf16* sm, const bf16* __restrict__ A, int lda, const bf16* __restrict__ B,
    int ldb, float* __restrict__ Cf, bf16* __restrict__ Cb, int ldc,
    int kStart, int kLen, int row0, int col0, int mLim) {
  constexpr int BISS = BN / 32;      // B 8-row issues per wave
  constexpr int LPT = 2 + BISS;      // gloads per wave per tile
  constexpr int NF = BN / 32;        // B fragments per wave
  constexpr int BUFE = (64 + BN) * 64;
  int tid = threadIdx.x;
  int lane = tid & 63, w = tid >> 6;
  int l16 = lane & 15, l4 = lane >> 4;
  int srow = lane >> 3;                // row within an 8-row issue
  int scol = ((lane & 7) ^ srow) * 8;  // inv-swizzled source granule
  int wr = (w & 1) * 32, wc = (w >> 1) * (BN / 2);
  const int arow0 = 16 * w;
  const int brow0 = 64 + (BN / 4) * w;
  const bf16* Ab = A + (long)row0 * lda + kStart;
  const bf16* Bb = B + (long)col0 * ldb + kStart;
  const bf16* aP[2];
  const bf16* bP[BISS];
#pragma unroll
  for (int a = 0; a < 2; ++a)
    aP[a] = Ab + (long)(arow0 + a * 8 + srow) * lda + scol;
#pragma unroll
  for (int b = 0; b < BISS; ++b)
    bP[b] = Bb + (long)((BN / 4) * w + b * 8 + srow) * ldb + scol;

  floatx4 acc[2][NF] = {};
  int NT = kLen >> 6;

#define STAGE(buf, kk)                                          \
  do {                                                          \
    bf16* bp_ = sm + (buf) * BUFE;                              \
    _Pragma("unroll") for (int a_ = 0; a_ < 2; ++a_)            \
        gload16(aP[a_] + (kk), bp_ + (arow0 + a_ * 8) * 64);    \
    _Pragma("unroll") for (int b_ = 0; b_ < BISS; ++b_)         \
        gload16(bP[b_] + (kk), bp_ + (brow0 + b_ * 8) * 64);    \
  } while (0)

  STAGE(0, 0);
  int sw = l16 & 7;  // read-side swizzle key (row&7)
  for (int t = 0; t < NT; ++t) {
    if (t + 1 < NT) {
      STAGE((t + 1) & 1, (t + 1) * 64);
      // in flight: tiles t, t+1 (2*LPT); leave LPT -> tile t landed
      asm volatile("s_waitcnt vmcnt(%0)" ::"n"(LPT) : "memory");
    } else {
      asm volatile("s_waitcnt vmcnt(0)" ::: "memory");  // tail drain
    }
    __builtin_amdgcn_s_barrier();       // all waves' tile-t DMA landed
    __builtin_amdgcn_sched_barrier(0);  // rule #18: no hoist above barrier
    const bf16* bp = sm + (t & 1) * BUFE;
#pragma unroll
    for (int h = 0; h < 2; ++h) {  // two K=32 halves of the 64-K tile
      short8 af[2], bg[NF];
#pragma unroll
      for (int g = 0; g < 2; ++g)
        af[g] = *(const short8*)(bp + (wr + g * 16 + l16) * 64 +
                                 ((h * 4 + l4) ^ sw) * 8);
#pragma unroll
      for (int h2 = 0; h2 < NF; ++h2)
        bg[h2] = *(const short8*)(bp + (64 + wc + h2 * 16 + l16) * 64 +
                                  ((h * 4 + l4) ^ sw) * 8);
#pragma unroll
      for (int g = 0; g < 2; ++g)
#pragma unroll
        for (int h2 = 0; h2 < NF; ++h2)
          acc[g][h2] = __builtin_amdgcn_mfma_f32_16x16x32_bf16(
              af[g], bg[h2], acc[g][h2], 0, 0, 0);
    }
    __builtin_amdgcn_sched_barrier(0);  // pin reads+mfma before barrier
    asm volatile("s_waitcnt lgkmcnt(0)" ::: "memory");  // reads retired
    __builtin_amdgcn_s_barrier();       // buf (t&1) reusable next iter
  }
#undef STAGE

  // C/D layout: col = lane&15, row = (lane>>4)*4 + i  [m89-verified]
#pragma unroll
  for (int g = 0; g < 2; ++g)
#pragma unroll
    for (int h = 0; h < NF; ++h)
#pragma unroll
      for (int i = 0; i < 4; ++i) {
        long r = row0 + wr + g * 16 + l4 * 4 + i;
        long c = col0 + wc + h * 16 + l16;
        if (r < mLim) {
          if (OUT == 0)
            Cf[r * ldc + c] = acc[g][h][i];
          else
            Cb[r * ldc + c] = __float2bfloat16(acc[g][h][i]);
        }
      }
}

// Merged QK (1024 blocks, 64x32) + Vt (512 blocks, 64x32) = 1536 blocks
// (~5-6/CU resident). K=2048 unsplit, direct bf16 output.
__global__ __launch_bounds__(256, 5) void gemm_qkvt(
    const bf16* __restrict__ Xb, const bf16* __restrict__ WqkT,
    const bf16* __restrict__ WvT, bf16* __restrict__ QKbf,
    bf16* __restrict__ Vtb) {
  __shared__ __align__(16) bf16 sm[2 * 96 * 64];  // 24 KB
  int id = blockIdx.x;
  if (id < 1024) {  // QK: C[512,4096] = Xb @ WqkT^T
    int row0 = (id >> 7) * 64, col0 = (id & 127) * 32;
    gemm_core<32, 1>(sm, Xb, DM, WqkT, DM, nullptr, QKbf, 4096, 0, DM, row0,
                     col0, MP);
  } else {  // Vt: C[2048,512] = WvT @ Xb^T
    int t = id - 1024;
    int row0 = (t >> 4) * 64, col0 = (t & 15) * 32;
    gemm_core<32, 1>(sm, WvT, DM, Xb, DM, nullptr, Vtb, MP, 0, DM, row0, col0,
                     DM);
  }
}

// Generic split-K gemm, 64x32 tiles. grid (N/32, M/64, splits).
template <int OUT>
__global__ __launch_bounds__(256, 5) void gemm_k(
    const bf16* __restrict__ A, int lda, const bf16* __restrict__ B, int ldb,
    float* __restrict__ Cf, bf16* __restrict__ Cb, int ldc, int sliceK,
    long cstride, int mLim) {
  __shared__ __align__(16) bf16 sm[2 * 96 * 64];  // 24 KB
  float* cf = (OUT == 0) ? Cf + (long)blockIdx.z * cstride : nullptr;
  gemm_core<32, OUT>(sm, A, lda, B, ldb, cf, Cb, ldc, blockIdx.z * sliceK,
                     sliceK, blockIdx.y * 64, blockIdx.x * 32, mLim);
}

// QR (21 dots of K=2048) + sum 8 S-partials + scale + bias + mask + softmax.
__global__ __launch_bounds__(256) void softmax_qr(
    const float* __restrict__ Sp, const bf16* __restrict__ QKbf,
    const bf16* __restrict__ wkb, const int* __restrict__ mask,
    float* __restrict__ Aout, bf16* __restrict__ Abf) {
  int i = blockIdx.x;
  int tid = threadIdx.x;
  if (i >= N_TOK) {  // pad rows of Abf -> 0
    Abf[(long)i * MP + tid] = __float2bfloat16(0.f);
    Abf[(long)i * MP + tid + 256] = __float2bfloat16(0.f);
    return;
  }
  int lane = tid & 63, w = tid >> 6;
  __shared__ float sQR[24];
  __shared__ float red[4];
  // ---- QR: wave w handles r = w, w+4, ... (Q row preloaded once) ----
  short8 q[4];
#pragma unroll
  for (int s = 0; s < 4; ++s)
    q[s] = *(const short8*)(QKbf + (long)i * 4096 + s * 512 + lane * 8);
  for (int r = w; r < NREL; r += 4) {
    float p = 0.f;
#pragma unroll
    for (int s = 0; s < 4; ++s) {
      short8 wv = *(const short8*)(wkb + (long)r * DM + s * 512 + lane * 8);
#pragma unroll
      for (int j = 0; j < 8; ++j) p += bfj(q[s], j) * bfj(wv, j);
    }
#pragma unroll
    for (int o = 32; o > 0; o >>= 1) p += __shfl_down(p, o);
    if (lane == 0) sQR[r] = p;
  }
  __syncthreads();
  // ---- softmax over j (each thread owns j0=tid, j1=tid+256) ----
  const float scale = 0.022097086912079608f;  // 1/sqrt(2048)
  float v0, v1 = -1e30f;
  int j0 = tid, j1 = tid + 256;
  {
    float s = 0.f;
#pragma unroll
    for (int z = 0; z < 8; ++z) s += Sp[z * NS + (long)i * MP + j0];
    int rel = j0 - i;
    rel = rel < -KWIN_ ? -KWIN_ : (rel > KWIN_ ? KWIN_ : rel);
    s = scale * (s + sQR[rel + KWIN_]);
    if (mask[(long)i * N_TOK + j0] == 0) s = -1e9f;
    v0 = s;
  }
  if (j1 < N_TOK) {
    float s = 0.f;
#pragma unroll
    for (int z = 0; z < 8; ++z) s += Sp[z * NS + (long)i * MP + j1];
    int rel = j1 - i;
    rel = rel < -KWIN_ ? -KWIN_ : (rel > KWIN_ ? KWIN_ : rel);
    s = scale * (s + sQR[rel + KWIN_]);
    if (mask[(long)i * N_TOK + j1] == 0) s = -1e9f;
    v1 = s;
  }
  float mx = fmaxf(v0, v1);
#pragma unroll
  for (int o = 32; o > 0; o >>= 1) mx = fmaxf(mx, __shfl_down(mx, o));
  if (lane == 0) red[w] = mx;
  __syncthreads();
  if (tid == 0) red[0] = fmaxf(fmaxf(red[0], red[1]), fmaxf(red[2], red[3]));
  __syncthreads();
  mx = red[0];
  __syncthreads();
  float e0 = expf(v0 - mx);
  float e1 = (j1 < N_TOK) ? expf(v1 - mx) : 0.f;
  float sum = e0 + e1;
#pragma unroll
  for (int o = 32; o > 0; o >>= 1) sum += __shfl_down(sum, o);
  if (lane == 0) red[w] = sum;
  __syncthreads();
  if (tid == 0) red[0] = red[0] + red[1] + red[2] + red[3];
  __syncthreads();
  float inv = 1.f / red[0];
  float a0 = e0 * inv, a1 = e1 * inv;
  Aout[(long)i * N_TOK + j0] = a0;
  if (j1 < N_TOK) Aout[(long)i * N_TOK + j1] = a1;
  Abf[(long)i * MP + j0] = __float2bfloat16(a0);
  Abf[(long)i * MP + j1] = __float2bfloat16(a1);  // j1>=500 -> 0
}

extern "C" void kernel_launch(void* const* d_in, const int* in_sizes, int n_in,
                              void* d_out, int out_size, void* d_ws,
                              size_t ws_size, hipStream_t stream) {
  const float* X = (const float*)d_in[0];
  const int* mask = (const int*)d_in[1];
  const float* Wq = (const float*)d_in[2];
  const float* Wk = (const float*)d_in[3];
  const float* Wv = (const float*)d_in[4];
  const float* Wo = (const float*)d_in[5];
  const float* wk = (const float*)d_in[6];

  float* Yout = (float*)d_out;            // [500,2048]
  float* Aout = Yout + (long)N_TOK * DM;  // [500,500]

  const long MB = 1 << 20;
  char* p = (char*)d_ws;
  bf16* Xb = (bf16*)p;                    // [512][2048]        2 MB
  bf16* WqkT = (bf16*)(p + 2 * MB);       // [4096][2048]      16 MB
  bf16* WvT = (bf16*)(p + 18 * MB);       // [2048][2048]       8 MB
  bf16* WoT = (bf16*)(p + 26 * MB);       // [2048][2048]       8 MB
  bf16* wkb = (bf16*)(p + 34 * MB);       // [21][2048]
  bf16* QKbf = (bf16*)(p + 35 * MB);      // [512][4096]        4 MB
  bf16* Vtb = (bf16*)(p + 39 * MB);       // [2048][512]        2 MB
  float* Sp = (float*)(p + 41 * MB);      // [8][512][512]      8 MB
  bf16* Abf = (bf16*)(p + 49 * MB);       // [512][512]       0.5 MB
  bf16* AVbf = (bf16*)(p + 50 * MB);      // [512][2048]        2 MB

  dim3 b256(256);

  // 1. prep: weights -> transposed bf16; X/wk -> bf16
  prep<<<dim3(32, 32, 5), b256, 0, stream>>>(Wq, Wk, Wv, Wo, X, wk, WqkT, WvT,
                                             WoT, Xb, wkb);
  // 2. QK (64x32, 1024 blk) + Vt (64x32, 512 blk) = 1536 blocks (~5-6/CU)
  gemm_qkvt<<<dim3(1536), b256, 0, stream>>>(Xb, WqkT, WvT, QKbf, Vtb);
  // 3. S partials: Q @ K^T, 64x32 tiles, splitK8 (sliceK=256, NT=4), 1024 blk
  gemm_k<0><<<dim3(16, 8, 8), b256, 0, stream>>>(
      QKbf, 4096, QKbf + 2048, 4096, Sp, nullptr, MP, 256, NS, MP);
  // 4. QR + softmax -> Aout (d_out) + Abf
  softmax_qr<<<dim3(MP), b256, 0, stream>>>(Sp, QKbf, wkb, mask, Aout, Abf);
  // 5. AV = Abf @ Vtb^T -> bf16, 64x32 tiles, 512 blocks (NT=8)
  gemm_k<1><<<dim3(64, 8, 1), b256, 0, stream>>>(
      Abf, MP, Vtb, MP, nullptr, AVbf, DM, MP, 0, MP);
  // 6. Y = AVbf @ WoT^T -> f32 d_out directly (rows < 500), 512 blocks, NT=32
  gemm_k<0><<<dim3(64, 8, 1), b256, 0, stream>>>(
      AVbf, DM, WoT, DM, Yout, nullptr, DM, DM, 0, N_TOK);
}

// Round 11
// 165.892 us; speedup vs baseline: 1.0426x; 1.0426x over previous
//
#include <hip/hip_runtime.h>
#include <hip/hip_bf16.h>

// RelationAwareSelfAttention  N=500, DM=DK=DV=2048, KWIN=10
// Round 17: R14 revert (best verified, 165.8us: BN=64/BK=64/D=3, 3/CU) +
// Y splitK2 via f32 partial buffer + reduce_y (R8-verified pattern; split-K
// adds no duplicate A/B traffic, unlike R16's tile-halving). 7 launches.

#define N_TOK 500
#define MP 512
#define DM 2048
#define KWIN_ 10
#define NREL 21

typedef __hip_bfloat16 bf16;
typedef __attribute__((ext_vector_type(8))) short short8;
typedef __attribute__((ext_vector_type(4))) float floatx4;

#define NS 262144L   // 512*512
#define NY 1048576L  // 512*2048

__device__ inline float bfj(const short8& v, int j) {
  return __bfloat162float(((const bf16*)&v)[j]);
}

__device__ __forceinline__ void gload16(const bf16* g, bf16* l) {
  __builtin_amdgcn_global_load_lds(
      (const __attribute__((address_space(1))) void*)g,
      (__attribute__((address_space(3))) void*)l, 16, 0, 0);
}

// ---------------- prep: weights transpose+cvt, X/wk cvt (verified) --------
__global__ __launch_bounds__(256) void prep(
    const float* __restrict__ Wq, const float* __restrict__ Wk,
    const float* __restrict__ Wv, const float* __restrict__ Wo,
    const float* __restrict__ X, const float* __restrict__ wk,
    bf16* __restrict__ WqkT, bf16* __restrict__ WvT, bf16* __restrict__ WoT,
    bf16* __restrict__ Xb, bf16* __restrict__ wkb) {
  int z = blockIdx.z;
  int tid = threadIdx.x;
  if (z == 4) {  // row conversions
    int row = blockIdx.y * 32 + blockIdx.x;
    int c0 = tid * 8;
    bf16 v[8];
    if (row < MP) {
      if (row < N_TOK) {
        const float* p = X + (long)row * DM + c0;
#pragma unroll
        for (int j = 0; j < 8; ++j) v[j] = __float2bfloat16(p[j]);
      } else {
#pragma unroll
        for (int j = 0; j < 8; ++j) v[j] = __float2bfloat16(0.f);
      }
      *(short8*)(Xb + (long)row * DM + c0) = *(short8*)v;
    } else if (row < MP + NREL) {
      int r = row - MP;
      const float* p = wk + (long)r * DM + c0;
#pragma unroll
      for (int j = 0; j < 8; ++j) v[j] = __float2bfloat16(p[j]);
      *(short8*)(wkb + (long)r * DM + c0) = *(short8*)v;
    }
    return;
  }
  const float* W = (z == 0) ? Wq : (z == 1) ? Wk : (z == 2) ? Wv : Wo;
  bf16* Out = (z == 0) ? WqkT
            : (z == 1) ? (WqkT + (long)DM * DM)
            : (z == 2) ? WvT : WoT;
  __shared__ float t[64][68];  // XOR-swizzled granules, conflict-free both sides
  int k0 = blockIdx.y * 64, n0 = blockIdx.x * 64;
  int rr = tid >> 4, cc = (tid & 15) * 4;
  int gsw = cc >> 2;
#pragma unroll
  for (int p = 0; p < 4; ++p) {
    int r = rr + 16 * p;
    float4 v = *(const float4*)(W + (long)(k0 + r) * DM + n0 + cc);
    *(float4*)&t[r][(gsw ^ (r & 3)) * 4] = v;
  }
  __syncthreads();
#pragma unroll
  for (int s0 = 0; s0 < 2; ++s0) {
    int s = tid + s0 * 256;
    int n = s >> 3, c = s & 7;  // 8 lanes per out row -> 128B contiguous
    bf16 v[8];
#pragma unroll
    for (int j = 0; j < 8; ++j) {
      int rowt = c * 8 + j;
      int col = ((n >> 2) ^ (rowt & 3)) * 4 + (n & 3);
      v[j] = __float2bfloat16(t[rowt][col]);
    }
    *(short8*)(Out + (long)(n0 + n) * DM + k0 + c * 8) = *(short8*)v;
  }
}

// ---------------- gemm core: 64xBN tile, BK=64, 3-deep gload_lds ----------
// C[M,N] = A[M,K] @ B[N,K]^T over K-slice [kStart, kStart+kLen).
// 4 waves 2x2; wave tile 32 x BN/2. BN=64: acc 2x2, LDS 48 KB, 3 blocks/CU.
// Staging: gload_lds issue = 64 lanes x 16B = 8 rows x 128B, linear dest.
// Swizzle: phys granule p of row r holds data granule p ^ (r&7); inverse
// permutation applied to the per-lane GLOBAL source granule (T21), same XOR
// on the LDS read -> <=2-way bank conflicts on ds_read_b128.
// Tile t staged at iter t-2; steady vmcnt leaves 2 tiles (2*LPT) in flight.
// OUT: 0 -> f32 store, 1 -> bf16 store. Store guard: row < mLim.
template <int BN, int OUT>
__device__ __forceinline__ void gemm_core(
    bf16* sm, const bf16* __restrict__ A, int lda, const bf16* __restrict__ B,
    int ldb, float* __restrict__ Cf, bf16* __restrict__ Cb, int ldc,
    int kStart, int kLen, int row0, int col0, int mLim) {
  constexpr int BISS = BN / 32;      // B 8-row issues per wave
  constexpr int LPT = 2 + BISS;      // gloads per wave per tile
  constexpr int NF = BN / 32;        // B fragments per wave
  constexpr int BUFE = (64 + BN) * 64;
  int tid = threadIdx.x;
  int lane = tid & 63, w = tid >> 6;
  int l16 = lane & 15, l4 = lane >> 4;
  int srow = lane >> 3;                // row within an 8-row issue
  int scol = ((lane & 7) ^ srow) * 8;  // inv-swizzled source granule
  int wr = (w & 1) * 32, wc = (w >> 1) * (BN / 2);
  const int arow0 = 16 * w;
  const int brow0 = 64 + (BN / 4) * w;
  const bf16* Ab = A + (long)row0 * lda + kStart;
  const bf16* Bb = B + (long)col0 * ldb + kStart;
  const bf16* aP[2];
  const bf16* bP[BISS];
#pragma unroll
  for (int a = 0; a < 2; ++a)
    aP[a] = Ab + (long)(arow0 + a * 8 + srow) * lda + scol;
#pragma unroll
  for (int b = 0; b < BISS; ++b)
    bP[b] = Bb + (long)((BN / 4) * w + b * 8 + srow) * ldb + scol;

  floatx4 acc[2][NF] = {};
  int NT = kLen >> 6;

#define STAGE(buf, kk)                                          \
  do {                                                          \
    bf16* bp_ = sm + (buf) * BUFE;                              \
    _Pragma("unroll") for (int a_ = 0; a_ < 2; ++a_)            \
        gload16(aP[a_] + (kk), bp_ + (arow0 + a_ * 8) * 64);    \
    _Pragma("unroll") for (int b_ = 0; b_ < BISS; ++b_)         \
        gload16(bP[b_] + (kk), bp_ + (brow0 + b_ * 8) * 64);    \
  } while (0)

  STAGE(0, 0);
  if (NT > 1) STAGE(1, 64);
  int bufr = 0, bufw = 2;
  int sw = l16 & 7;  // read-side swizzle key (row&7)
  for (int t = 0; t < NT; ++t) {
    if (t + 2 < NT) {
      STAGE(bufw, (t + 2) * 64);
      // in flight: tiles t, t+1, t+2 (3*LPT); leave 2*LPT -> tile t landed
      asm volatile("s_waitcnt vmcnt(%0)" ::"n"(2 * LPT) : "memory");
    } else {
      asm volatile("s_waitcnt vmcnt(0)" ::: "memory");  // tail drain
    }
    __builtin_amdgcn_s_barrier();       // all waves' tile-t DMA landed
    __builtin_amdgcn_sched_barrier(0);  // rule #18: no hoist above barrier
    const bf16* bp = sm + bufr * BUFE;
#pragma unroll
    for (int h = 0; h < 2; ++h) {  // two K=32 halves of the 64-K tile
      short8 af[2], bg[NF];
#pragma unroll
      for (int g = 0; g < 2; ++g)
        af[g] = *(const short8*)(bp + (wr + g * 16 + l16) * 64 +
                                 ((h * 4 + l4) ^ sw) * 8);
#pragma unroll
      for (int h2 = 0; h2 < NF; ++h2)
        bg[h2] = *(const short8*)(bp + (64 + wc + h2 * 16 + l16) * 64 +
                                  ((h * 4 + l4) ^ sw) * 8);
#pragma unroll
      for (int g = 0; g < 2; ++g)
#pragma unroll
        for (int h2 = 0; h2 < NF; ++h2)
          acc[g][h2] = __builtin_amdgcn_mfma_f32_16x16x32_bf16(
              af[g], bg[h2], acc[g][h2], 0, 0, 0);
    }
    __builtin_amdgcn_sched_barrier(0);  // pin reads+mfma before barrier
    asm volatile("s_waitcnt lgkmcnt(0)" ::: "memory");  // reads retired
    __builtin_amdgcn_s_barrier();       // buf reuse safe next iter
    bufr = (bufr == 2) ? 0 : bufr + 1;
    bufw = (bufw == 2) ? 0 : bufw + 1;
  }
#undef STAGE

  // C/D layout: col = lane&15, row = (lane>>4)*4 + i  [m89-verified]
#pragma unroll
  for (int g = 0; g < 2; ++g)
#pragma unroll
    for (int h = 0; h < NF; ++h)
#pragma unroll
      for (int i = 0; i < 4; ++i) {
        long r = row0 + wr + g * 16 + l4 * 4 + i;
        long c = col0 + wc + h * 16 + l16;
        if (r < mLim) {
          if (OUT == 0)
            Cf[r * ldc + c] = acc[g][h][i];
          else
            Cb[r * ldc + c] = __float2bfloat16(acc[g][h][i]);
        }
      }
}

// Merged QK (512 blocks, 64x64) + Vt (256 blocks, 64x64) = 768 blocks
// = exactly 3 blocks/CU resident. K=2048 unsplit, direct bf16 output.
__global__ __launch_bounds__(256, 3) void gemm_qkvt(
    const bf16* __restrict__ Xb, const bf16* __restrict__ WqkT,
    const bf16* __restrict__ WvT, bf16* __restrict__ QKbf,
    bf16* __restrict__ Vtb) {
  __shared__ __align__(16) bf16 sm[3 * 128 * 64];  // 48 KB
  int id = blockIdx.x;
  if (id < 512) {  // QK: C[512,4096] = Xb @ WqkT^T
    int row0 = (id >> 6) * 64, col0 = (id & 63) * 64;
    gemm_core<64, 1>(sm, Xb, DM, WqkT, DM, nullptr, QKbf, 4096, 0, DM, row0,
                     col0, MP);
  } else {  // Vt: C[2048,512] = WvT @ Xb^T
    int t = id - 512;
    int row0 = (t >> 3) * 64, col0 = (t & 7) * 64;
    gemm_core<64, 1>(sm, WvT, DM, Xb, DM, nullptr, Vtb, MP, 0, DM, row0, col0,
                     DM);
  }
}

// Generic split-K gemm, 64x64 tiles. grid (N/64, M/64, splits).
template <int OUT>
__global__ __launch_bounds__(256, 3) void gemm_k(
    const bf16* __restrict__ A, int lda, const bf16* __restrict__ B, int ldb,
    float* __restrict__ Cf, bf16* __restrict__ Cb, int ldc, int sliceK,
    long cstride, int mLim) {
  __shared__ __align__(16) bf16 sm[3 * 128 * 64];  // 48 KB
  float* cf = (OUT == 0) ? Cf + (long)blockIdx.z * cstride : nullptr;
  gemm_core<64, OUT>(sm, A, lda, B, ldb, cf, Cb, ldc, blockIdx.z * sliceK,
                     sliceK, blockIdx.y * 64, blockIdx.x * 64, mLim);
}

// Yout[<500] = Yp[0] + Yp[1]. grid 500 x 256.
__global__ __launch_bounds__(256) void reduce_y(const float* __restrict__ Yp,
                                                float* __restrict__ Yout) {
  long e = (long)blockIdx.x * DM + threadIdx.x * 8;
  float4 a0 = *(const float4*)(Yp + e), a1 = *(const float4*)(Yp + e + 4);
  float4 b0 = *(const float4*)(Yp + NY + e),
         b1 = *(const float4*)(Yp + NY + e + 4);
  float4 o0 = {a0.x + b0.x, a0.y + b0.y, a0.z + b0.z, a0.w + b0.w};
  float4 o1 = {a1.x + b1.x, a1.y + b1.y, a1.z + b1.z, a1.w + b1.w};
  *(float4*)(Yout + e) = o0;
  *(float4*)(Yout + e + 4) = o1;
}

// QR (21 dots of K=2048) + sum 8 S-partials + scale + bias + mask + softmax.
__global__ __launch_bounds__(256) void softmax_qr(
    const float* __restrict__ Sp, const bf16* __restrict__ QKbf,
    const bf16* __restrict__ wkb, const int* __restrict__ mask,
    float* __restrict__ Aout, bf16* __restrict__ Abf) {
  int i = blockIdx.x;
  int tid = threadIdx.x;
  if (i >= N_TOK) {  // pad rows of Abf -> 0
    Abf[(long)i * MP + tid] = __float2bfloat16(0.f);
    Abf[(long)i * MP + tid + 256] = __float2bfloat16(0.f);
    return;
  }
  int lane = tid & 63, w = tid >> 6;
  __shared__ float sQR[24];
  __shared__ float red[4];
  // ---- QR: wave w handles r = w, w+4, ... (Q row preloaded once) ----
  short8 q[4];
#pragma unroll
  for (int s = 0; s < 4; ++s)
    q[s] = *(const short8*)(QKbf + (long)i * 4096 + s * 512 + lane * 8);
  for (int r = w; r < NREL; r += 4) {
    float p = 0.f;
#pragma unroll
    for (int s = 0; s < 4; ++s) {
      short8 wv = *(const short8*)(wkb + (long)r * DM + s * 512 + lane * 8);
#pragma unroll
      for (int j = 0; j < 8; ++j) p += bfj(q[s], j) * bfj(wv, j);
    }
#pragma unroll
    for (int o = 32; o > 0; o >>= 1) p += __shfl_down(p, o);
    if (lane == 0) sQR[r] = p;
  }
  __syncthreads();
  // ---- softmax over j (each thread owns j0=tid, j1=tid+256) ----
  const float scale = 0.022097086912079608f;  // 1/sqrt(2048)
  float v0, v1 = -1e30f;
  int j0 = tid, j1 = tid + 256;
  {
    float s = 0.f;
#pragma unroll
    for (int z = 0; z < 8; ++z) s += Sp[z * NS + (long)i * MP + j0];
    int rel = j0 - i;
    rel = rel < -KWIN_ ? -KWIN_ : (rel > KWIN_ ? KWIN_ : rel);
    s = scale * (s + sQR[rel + KWIN_]);
    if (mask[(long)i * N_TOK + j0] == 0) s = -1e9f;
    v0 = s;
  }
  if (j1 < N_TOK) {
    float s = 0.f;
#pragma unroll
    for (int z = 0; z < 8; ++z) s += Sp[z * NS + (long)i * MP + j1];
    int rel = j1 - i;
    rel = rel < -KWIN_ ? -KWIN_ : (rel > KWIN_ ? KWIN_ : rel);
    s = scale * (s + sQR[rel + KWIN_]);
    if (mask[(long)i * N_TOK + j1] == 0) s = -1e9f;
    v1 = s;
  }
  float mx = fmaxf(v0, v1);
#pragma unroll
  for (int o = 32; o > 0; o >>= 1) mx = fmaxf(mx, __shfl_down(mx, o));
  if (lane == 0) red[w] = mx;
  __syncthreads();
  if (tid == 0) red[0] = fmaxf(fmaxf(red[0], red[1]), fmaxf(red[2], red[3]));
  __syncthreads();
  mx = red[0];
  __syncthreads();
  float e0 = expf(v0 - mx);
  float e1 = (j1 < N_TOK) ? expf(v1 - mx) : 0.f;
  float sum = e0 + e1;
#pragma unroll
  for (int o = 32; o > 0; o >>= 1) sum += __shfl_down(sum, o);
  if (lane == 0) red[w] = sum;
  __syncthreads();
  if (tid == 0) red[0] = red[0] + red[1] + red[2] + red[3];
  __syncthreads();
  float inv = 1.f / red[0];
  float a0 = e0 * inv, a1 = e1 * inv;
  Aout[(long)i * N_TOK + j0] = a0;
  if (j1 < N_TOK) Aout[(long)i * N_TOK + j1] = a1;
  Abf[(long)i * MP + j0] = __float2bfloat16(a0);
  Abf[(long)i * MP + j1] = __float2bfloat16(a1);  // j1>=500 -> 0
}

extern "C" void kernel_launch(void* const* d_in, const int* in_sizes, int n_in,
                              void* d_out, int out_size, void* d_ws,
                              size_t ws_size, hipStream_t stream) {
  const float* X = (const float*)d_in[0];
  const int* mask = (const int*)d_in[1];
  const float* Wq = (const float*)d_in[2];
  const float* Wk = (const float*)d_in[3];
  const float* Wv = (const float*)d_in[4];
  const float* Wo = (const float*)d_in[5];
  const float* wk = (const float*)d_in[6];

  float* Yout = (float*)d_out;            // [500,2048]
  float* Aout = Yout + (long)N_TOK * DM;  // [500,500]

  const long MB = 1 << 20;
  char* p = (char*)d_ws;
  bf16* Xb = (bf16*)p;                    // [512][2048]        2 MB
  bf16* WqkT = (bf16*)(p + 2 * MB);       // [4096][2048]      16 MB
  bf16* WvT = (bf16*)(p + 18 * MB);       // [2048][2048]       8 MB
  bf16* WoT = (bf16*)(p + 26 * MB);       // [2048][2048]       8 MB
  bf16* wkb = (bf16*)(p + 34 * MB);       // [21][2048]
  bf16* QKbf = (bf16*)(p + 35 * MB);      // [512][4096]        4 MB
  bf16* Vtb = (bf16*)(p + 39 * MB);       // [2048][512]        2 MB
  float* Sp = (float*)(p + 41 * MB);      // [8][512][512]      8 MB
  bf16* Abf = (bf16*)(p + 49 * MB);       // [512][512]       0.5 MB
  bf16* AVbf = (bf16*)(p + 50 * MB);      // [512][2048]        2 MB
  float* Yp = (float*)(p + 52 * MB);      // [2][512][2048]     8 MB

  dim3 b256(256);

  // 1. prep: weights -> transposed bf16; X/wk -> bf16
  prep<<<dim3(32, 32, 5), b256, 0, stream>>>(Wq, Wk, Wv, Wo, X, wk, WqkT, WvT,
                                             WoT, Xb, wkb);
  // 2. QK (64x64, 512 blk) + Vt (64x64, 256 blk) = 768 blocks (3/CU)
  gemm_qkvt<<<dim3(768), b256, 0, stream>>>(Xb, WqkT, WvT, QKbf, Vtb);
  // 3. S partials: Q @ K^T, 64x64 tiles, splitK8 (sliceK=256, NT=4), 512 blk
  gemm_k<0><<<dim3(8, 8, 8), b256, 0, stream>>>(
      QKbf, 4096, QKbf + 2048, 4096, Sp, nullptr, MP, 256, NS, MP);
  // 4. QR + softmax -> Aout (d_out) + Abf
  softmax_qr<<<dim3(MP), b256, 0, stream>>>(Sp, QKbf, wkb, mask, Aout, Abf);
  // 5. AV = Abf @ Vtb^T -> bf16, 64x64 tiles, 256 blocks (NT=8)
  gemm_k<1><<<dim3(32, 8, 1), b256, 0, stream>>>(
      Abf, MP, Vtb, MP, nullptr, AVbf, DM, MP, 0, MP);
  // 6. Y partials: AVbf @ WoT^T, splitK2 (sliceK=1024, NT=16), 512 blk (2/CU)
  gemm_k<0><<<dim3(32, 8, 2), b256, 0, stream>>>(
      AVbf, DM, WoT, DM, Yp, nullptr, DM, 1024, NY, MP);
  // 7. Yout[<500] = Yp[0] + Yp[1]
  reduce_y<<<dim3(N_TOK), b256, 0, stream>>>(Yp, Yout);
}

// Round 12
// 165.205 us; speedup vs baseline: 1.0469x; 1.0042x over previous
//
#include <hip/hip_runtime.h>
#include <hip/hip_bf16.h>

// RelationAwareSelfAttention  N=500, DM=DK=DV=2048, KWIN=10
// Round 18: final lock-in of the converged optimum = R14 exactly.
// BN=64/BK=64/D=3 gload_lds core, 3 blocks/CU (qkvt 768 blk), S splitK8,
// AV 256, Y 256 unsplit direct-store (R17's splitK2+reduce measured net-0).
// 6 launches. Session ledger: ~83us harness fills (fixed) + ~83us kernels.

#define N_TOK 500
#define MP 512
#define DM 2048
#define KWIN_ 10
#define NREL 21

typedef __hip_bfloat16 bf16;
typedef __attribute__((ext_vector_type(8))) short short8;
typedef __attribute__((ext_vector_type(4))) float floatx4;

#define NS 262144L  // 512*512

__device__ inline float bfj(const short8& v, int j) {
  return __bfloat162float(((const bf16*)&v)[j]);
}

__device__ __forceinline__ void gload16(const bf16* g, bf16* l) {
  __builtin_amdgcn_global_load_lds(
      (const __attribute__((address_space(1))) void*)g,
      (__attribute__((address_space(3))) void*)l, 16, 0, 0);
}

// ---------------- prep: weights transpose+cvt, X/wk cvt (verified) --------
__global__ __launch_bounds__(256) void prep(
    const float* __restrict__ Wq, const float* __restrict__ Wk,
    const float* __restrict__ Wv, const float* __restrict__ Wo,
    const float* __restrict__ X, const float* __restrict__ wk,
    bf16* __restrict__ WqkT, bf16* __restrict__ WvT, bf16* __restrict__ WoT,
    bf16* __restrict__ Xb, bf16* __restrict__ wkb) {
  int z = blockIdx.z;
  int tid = threadIdx.x;
  if (z == 4) {  // row conversions
    int row = blockIdx.y * 32 + blockIdx.x;
    int c0 = tid * 8;
    bf16 v[8];
    if (row < MP) {
      if (row < N_TOK) {
        const float* p = X + (long)row * DM + c0;
#pragma unroll
        for (int j = 0; j < 8; ++j) v[j] = __float2bfloat16(p[j]);
      } else {
#pragma unroll
        for (int j = 0; j < 8; ++j) v[j] = __float2bfloat16(0.f);
      }
      *(short8*)(Xb + (long)row * DM + c0) = *(short8*)v;
    } else if (row < MP + NREL) {
      int r = row - MP;
      const float* p = wk + (long)r * DM + c0;
#pragma unroll
      for (int j = 0; j < 8; ++j) v[j] = __float2bfloat16(p[j]);
      *(short8*)(wkb + (long)r * DM + c0) = *(short8*)v;
    }
    return;
  }
  const float* W = (z == 0) ? Wq : (z == 1) ? Wk : (z == 2) ? Wv : Wo;
  bf16* Out = (z == 0) ? WqkT
            : (z == 1) ? (WqkT + (long)DM * DM)
            : (z == 2) ? WvT : WoT;
  __shared__ float t[64][68];  // XOR-swizzled granules, conflict-free both sides
  int k0 = blockIdx.y * 64, n0 = blockIdx.x * 64;
  int rr = tid >> 4, cc = (tid & 15) * 4;
  int gsw = cc >> 2;
#pragma unroll
  for (int p = 0; p < 4; ++p) {
    int r = rr + 16 * p;
    float4 v = *(const float4*)(W + (long)(k0 + r) * DM + n0 + cc);
    *(float4*)&t[r][(gsw ^ (r & 3)) * 4] = v;
  }
  __syncthreads();
#pragma unroll
  for (int s0 = 0; s0 < 2; ++s0) {
    int s = tid + s0 * 256;
    int n = s >> 3, c = s & 7;  // 8 lanes per out row -> 128B contiguous
    bf16 v[8];
#pragma unroll
    for (int j = 0; j < 8; ++j) {
      int rowt = c * 8 + j;
      int col = ((n >> 2) ^ (rowt & 3)) * 4 + (n & 3);
      v[j] = __float2bfloat16(t[rowt][col]);
    }
    *(short8*)(Out + (long)(n0 + n) * DM + k0 + c * 8) = *(short8*)v;
  }
}

// ---------------- gemm core: 64xBN tile, BK=64, 3-deep gload_lds ----------
// C[M,N] = A[M,K] @ B[N,K]^T over K-slice [kStart, kStart+kLen).
// 4 waves 2x2; wave tile 32 x BN/2. BN=64: acc 2x2, LDS 48 KB, 3 blocks/CU.
// Staging: gload_lds issue = 64 lanes x 16B = 8 rows x 128B, linear dest.
// Swizzle: phys granule p of row r holds data granule p ^ (r&7); inverse
// permutation applied to the per-lane GLOBAL source granule (T21), same XOR
// on the LDS read -> <=2-way bank conflicts on ds_read_b128.
// Tile t staged at iter t-2; steady vmcnt leaves 2 tiles (2*LPT) in flight.
// OUT: 0 -> f32 store, 1 -> bf16 store. Store guard: row < mLim.
template <int BN, int OUT>
__device__ __forceinline__ void gemm_core(
    bf16* sm, const bf16* __restrict__ A, int lda, const bf16* __restrict__ B,
    int ldb, float* __restrict__ Cf, bf16* __restrict__ Cb, int ldc,
    int kStart, int kLen, int row0, int col0, int mLim) {
  constexpr int BISS = BN / 32;      // B 8-row issues per wave
  constexpr int LPT = 2 + BISS;      // gloads per wave per tile
  constexpr int NF = BN / 32;        // B fragments per wave
  constexpr int BUFE = (64 + BN) * 64;
  int tid = threadIdx.x;
  int lane = tid & 63, w = tid >> 6;
  int l16 = lane & 15, l4 = lane >> 4;
  int srow = lane >> 3;                // row within an 8-row issue
  int scol = ((lane & 7) ^ srow) * 8;  // inv-swizzled source granule
  int wr = (w & 1) * 32, wc = (w >> 1) * (BN / 2);
  const int arow0 = 16 * w;
  const int brow0 = 64 + (BN / 4) * w;
  const bf16* Ab = A + (long)row0 * lda + kStart;
  const bf16* Bb = B + (long)col0 * ldb + kStart;
  const bf16* aP[2];
  const bf16* bP[BISS];
#pragma unroll
  for (int a = 0; a < 2; ++a)
    aP[a] = Ab + (long)(arow0 + a * 8 + srow) * lda + scol;
#pragma unroll
  for (int b = 0; b < BISS; ++b)
    bP[b] = Bb + (long)((BN / 4) * w + b * 8 + srow) * ldb + scol;

  floatx4 acc[2][NF] = {};
  int NT = kLen >> 6;

#define STAGE(buf, kk)                                          \
  do {                                                          \
    bf16* bp_ = sm + (buf) * BUFE;                              \
    _Pragma("unroll") for (int a_ = 0; a_ < 2; ++a_)            \
        gload16(aP[a_] + (kk), bp_ + (arow0 + a_ * 8) * 64);    \
    _Pragma("unroll") for (int b_ = 0; b_ < BISS; ++b_)         \
        gload16(bP[b_] + (kk), bp_ + (brow0 + b_ * 8) * 64);    \
  } while (0)

  STAGE(0, 0);
  if (NT > 1) STAGE(1, 64);
  int bufr = 0, bufw = 2;
  int sw = l16 & 7;  // read-side swizzle key (row&7)
  for (int t = 0; t < NT; ++t) {
    if (t + 2 < NT) {
      STAGE(bufw, (t + 2) * 64);
      // in flight: tiles t, t+1, t+2 (3*LPT); leave 2*LPT -> tile t landed
      asm volatile("s_waitcnt vmcnt(%0)" ::"n"(2 * LPT) : "memory");
    } else {
      asm volatile("s_waitcnt vmcnt(0)" ::: "memory");  // tail drain
    }
    __builtin_amdgcn_s_barrier();       // all waves' tile-t DMA landed
    __builtin_amdgcn_sched_barrier(0);  // rule #18: no hoist above barrier
    const bf16* bp = sm + bufr * BUFE;
#pragma unroll
    for (int h = 0; h < 2; ++h) {  // two K=32 halves of the 64-K tile
      short8 af[2], bg[NF];
#pragma unroll
      for (int g = 0; g < 2; ++g)
        af[g] = *(const short8*)(bp + (wr + g * 16 + l16) * 64 +
                                 ((h * 4 + l4) ^ sw) * 8);
#pragma unroll
      for (int h2 = 0; h2 < NF; ++h2)
        bg[h2] = *(const short8*)(bp + (64 + wc + h2 * 16 + l16) * 64 +
                                  ((h * 4 + l4) ^ sw) * 8);
#pragma unroll
      for (int g = 0; g < 2; ++g)
#pragma unroll
        for (int h2 = 0; h2 < NF; ++h2)
          acc[g][h2] = __builtin_amdgcn_mfma_f32_16x16x32_bf16(
              af[g], bg[h2], acc[g][h2], 0, 0, 0);
    }
    __builtin_amdgcn_sched_barrier(0);  // pin reads+mfma before barrier
    asm volatile("s_waitcnt lgkmcnt(0)" ::: "memory");  // reads retired
    __builtin_amdgcn_s_barrier();       // buf reuse safe next iter
    bufr = (bufr == 2) ? 0 : bufr + 1;
    bufw = (bufw == 2) ? 0 : bufw + 1;
  }
#undef STAGE

  // C/D layout: col = lane&15, row = (lane>>4)*4 + i  [m89-verified]
#pragma unroll
  for (int g = 0; g < 2; ++g)
#pragma unroll
    for (int h = 0; h < NF; ++h)
#pragma unroll
      for (int i = 0; i < 4; ++i) {
        long r = row0 + wr + g * 16 + l4 * 4 + i;
        long c = col0 + wc + h * 16 + l16;
        if (r < mLim) {
          if (OUT == 0)
            Cf[r * ldc + c] = acc[g][h][i];
          else
            Cb[r * ldc + c] = __float2bfloat16(acc[g][h][i]);
        }
      }
}

// Merged QK (512 blocks, 64x64) + Vt (256 blocks, 64x64) = 768 blocks
// = exactly 3 blocks/CU resident. K=2048 unsplit, direct bf16 output.
__global__ __launch_bounds__(256, 3) void gemm_qkvt(
    const bf16* __restrict__ Xb, const bf16* __restrict__ WqkT,
    const bf16* __restrict__ WvT, bf16* __restrict__ QKbf,
    bf16* __restrict__ Vtb) {
  __shared__ __align__(16) bf16 sm[3 * 128 * 64];  // 48 KB
  int id = blockIdx.x;
  if (id < 512) {  // QK: C[512,4096] = Xb @ WqkT^T
    int row0 = (id >> 6) * 64, col0 = (id & 63) * 64;
    gemm_core<64, 1>(sm, Xb, DM, WqkT, DM, nullptr, QKbf, 4096, 0, DM, row0,
                     col0, MP);
  } else {  // Vt: C[2048,512] = WvT @ Xb^T
    int t = id - 512;
    int row0 = (t >> 3) * 64, col0 = (t & 7) * 64;
    gemm_core<64, 1>(sm, WvT, DM, Xb, DM, nullptr, Vtb, MP, 0, DM, row0, col0,
                     DM);
  }
}

// Generic split-K gemm, 64x64 tiles. grid (N/64, M/64, splits).
template <int OUT>
__global__ __launch_bounds__(256, 3) void gemm_k(
    const bf16* __restrict__ A, int lda, const bf16* __restrict__ B, int ldb,
    float* __restrict__ Cf, bf16* __restrict__ Cb, int ldc, int sliceK,
    long cstride, int mLim) {
  __shared__ __align__(16) bf16 sm[3 * 128 * 64];  // 48 KB
  float* cf = (OUT == 0) ? Cf + (long)blockIdx.z * cstride : nullptr;
  gemm_core<64, OUT>(sm, A, lda, B, ldb, cf, Cb, ldc, blockIdx.z * sliceK,
                     sliceK, blockIdx.y * 64, blockIdx.x * 64, mLim);
}

// QR (21 dots of K=2048) + sum 8 S-partials + scale + bias + mask + softmax.
__global__ __launch_bounds__(256) void softmax_qr(
    const float* __restrict__ Sp, const bf16* __restrict__ QKbf,
    const bf16* __restrict__ wkb, const int* __restrict__ mask,
    float* __restrict__ Aout, bf16* __restrict__ Abf) {
  int i = blockIdx.x;
  int tid = threadIdx.x;
  if (i >= N_TOK) {  // pad rows of Abf -> 0
    Abf[(long)i * MP + tid] = __float2bfloat16(0.f);
    Abf[(long)i * MP + tid + 256] = __float2bfloat16(0.f);
    return;
  }
  int lane = tid & 63, w = tid >> 6;
  __shared__ float sQR[24];
  __shared__ float red[4];
  // ---- QR: wave w handles r = w, w+4, ... (Q row preloaded once) ----
  short8 q[4];
#pragma unroll
  for (int s = 0; s < 4; ++s)
    q[s] = *(const short8*)(QKbf + (long)i * 4096 + s * 512 + lane * 8);
  for (int r = w; r < NREL; r += 4) {
    float p = 0.f;
#pragma unroll
    for (int s = 0; s < 4; ++s) {
      short8 wv = *(const short8*)(wkb + (long)r * DM + s * 512 + lane * 8);
#pragma unroll
      for (int j = 0; j < 8; ++j) p += bfj(q[s], j) * bfj(wv, j);
    }
#pragma unroll
    for (int o = 32; o > 0; o >>= 1) p += __shfl_down(p, o);
    if (lane == 0) sQR[r] = p;
  }
  __syncthreads();
  // ---- softmax over j (each thread owns j0=tid, j1=tid+256) ----
  const float scale = 0.022097086912079608f;  // 1/sqrt(2048)
  float v0, v1 = -1e30f;
  int j0 = tid, j1 = tid + 256;
  {
    float s = 0.f;
#pragma unroll
    for (int z = 0; z < 8; ++z) s += Sp[z * NS + (long)i * MP + j0];
    int rel = j0 - i;
    rel = rel < -KWIN_ ? -KWIN_ : (rel > KWIN_ ? KWIN_ : rel);
    s = scale * (s + sQR[rel + KWIN_]);
    if (mask[(long)i * N_TOK + j0] == 0) s = -1e9f;
    v0 = s;
  }
  if (j1 < N_TOK) {
    float s = 0.f;
#pragma unroll
    for (int z = 0; z < 8; ++z) s += Sp[z * NS + (long)i * MP + j1];
    int rel = j1 - i;
    rel = rel < -KWIN_ ? -KWIN_ : (rel > KWIN_ ? KWIN_ : rel);
    s = scale * (s + sQR[rel + KWIN_]);
    if (mask[(long)i * N_TOK + j1] == 0) s = -1e9f;
    v1 = s;
  }
  float mx = fmaxf(v0, v1);
#pragma unroll
  for (int o = 32; o > 0; o >>= 1) mx = fmaxf(mx, __shfl_down(mx, o));
  if (lane == 0) red[w] = mx;
  __syncthreads();
  if (tid == 0) red[0] = fmaxf(fmaxf(red[0], red[1]), fmaxf(red[2], red[3]));
  __syncthreads();
  mx = red[0];
  __syncthreads();
  float e0 = expf(v0 - mx);
  float e1 = (j1 < N_TOK) ? expf(v1 - mx) : 0.f;
  float sum = e0 + e1;
#pragma unroll
  for (int o = 32; o > 0; o >>= 1) sum += __shfl_down(sum, o);
  if (lane == 0) red[w] = sum;
  __syncthreads();
  if (tid == 0) red[0] = red[0] + red[1] + red[2] + red[3];
  __syncthreads();
  float inv = 1.f / red[0];
  float a0 = e0 * inv, a1 = e1 * inv;
  Aout[(long)i * N_TOK + j0] = a0;
  if (j1 < N_TOK) Aout[(long)i * N_TOK + j1] = a1;
  Abf[(long)i * MP + j0] = __float2bfloat16(a0);
  Abf[(long)i * MP + j1] = __float2bfloat16(a1);  // j1>=500 -> 0
}

extern "C" void kernel_launch(void* const* d_in, const int* in_sizes, int n_in,
                              void* d_out, int out_size, void* d_ws,
                              size_t ws_size, hipStream_t stream) {
  const float* X = (const float*)d_in[0];
  const int* mask = (const int*)d_in[1];
  const float* Wq = (const float*)d_in[2];
  const float* Wk = (const float*)d_in[3];
  const float* Wv = (const float*)d_in[4];
  const float* Wo = (const float*)d_in[5];
  const float* wk = (const float*)d_in[6];

  float* Yout = (float*)d_out;            // [500,2048]
  float* Aout = Yout + (long)N_TOK * DM;  // [500,500]

  const long MB = 1 << 20;
  char* p = (char*)d_ws;
  bf16* Xb = (bf16*)p;                    // [512][2048]        2 MB
  bf16* WqkT = (bf16*)(p + 2 * MB);       // [4096][2048]      16 MB
  bf16* WvT = (bf16*)(p + 18 * MB);       // [2048][2048]       8 MB
  bf16* WoT = (bf16*)(p + 26 * MB);       // [2048][2048]       8 MB
  bf16* wkb = (bf16*)(p + 34 * MB);       // [21][2048]
  bf16* QKbf = (bf16*)(p + 35 * MB);      // [512][4096]        4 MB
  bf16* Vtb = (bf16*)(p + 39 * MB);       // [2048][512]        2 MB
  float* Sp = (float*)(p + 41 * MB);      // [8][512][512]      8 MB
  bf16* Abf = (bf16*)(p + 49 * MB);       // [512][512]       0.5 MB
  bf16* AVbf = (bf16*)(p + 50 * MB);      // [512][2048]        2 MB

  dim3 b256(256);

  // 1. prep: weights -> transposed bf16; X/wk -> bf16
  prep<<<dim3(32, 32, 5), b256, 0, stream>>>(Wq, Wk, Wv, Wo, X, wk, WqkT, WvT,
                                             WoT, Xb, wkb);
  // 2. QK (64x64, 512 blk) + Vt (64x64, 256 blk) = 768 blocks (3/CU)
  gemm_qkvt<<<dim3(768), b256, 0, stream>>>(Xb, WqkT, WvT, QKbf, Vtb);
  // 3. S partials: Q @ K^T, 64x64 tiles, splitK8 (sliceK=256, NT=4), 512 blk
  gemm_k<0><<<dim3(8, 8, 8), b256, 0, stream>>>(
      QKbf, 4096, QKbf + 2048, 4096, Sp, nullptr, MP, 256, NS, MP);
  // 4. QR + softmax -> Aout (d_out) + Abf
  softmax_qr<<<dim3(MP), b256, 0, stream>>>(Sp, QKbf, wkb, mask, Aout, Abf);
  // 5. AV = Abf @ Vtb^T -> bf16, 64x64 tiles, 256 blocks (NT=8)
  gemm_k<1><<<dim3(32, 8, 1), b256, 0, stream>>>(
      Abf, MP, Vtb, MP, nullptr, AVbf, DM, MP, 0, MP);
  // 6. Y = AVbf @ WoT^T -> f32 d_out directly (rows < 500), 256 blocks, NT=32
  gemm_k<0><<<dim3(32, 8, 1), b256, 0, stream>>>(
      AVbf, DM, WoT, DM, Yout, nullptr, DM, DM, 0, N_TOK);
}